// Round 13
// baseline (240.772 us; speedup 1.0000x reference)
//
#include <hip/hip_runtime.h>
#include <hip/hip_cooperative_groups.h>
#include <math.h>
#include <stdint.h>

namespace cg = cooperative_groups;

#define NLV 16
#define LOG2T 19
#define TSZ (1u << LOG2T)
#define TMASK (TSZ - 1u)
#define PRIME_Y 2654435761u

// weight frags: W0 as 4 fp8-u64 frags; W1/W2 as 10 bf16x8 frags
#define WP8_BYTES  (4 * 64 * 8)      // 2048
#define WP16_BYTES (10 * 64 * 16)    // 10240
#define WPF_BYTES  (WP8_BYTES + WP16_BYTES)

#define FSCALE 8192.0f               // 2^13 feature pre-scale for fp8
#define FUNSCALE (1.0f / 8192.0f)

#define NCOARSE 512            // 9-bit y-tile
#define P1_PTS 8192            // points per sort block
#define P2_CAP 5120            // fallback pass-2 cap

struct NGPParams {
    float scale[NLV];
    unsigned res[NLV];
    unsigned hashed_mask;
};

struct __align__(8) pairld { float x, y, z, w; };   // 16B, 8B-aligned load

typedef __attribute__((ext_vector_type(8))) short bf16x8;
typedef __attribute__((ext_vector_type(4))) float f32x4;

__device__ inline ushort bf16_rn(float f) {
    uint32_t u = __float_as_uint(f);
    return (ushort)((u + 0x7FFFu + ((u >> 16) & 1u)) >> 16);
}
__device__ inline uint32_t pack_trunc(float a, float b) {
    return __builtin_amdgcn_perm(__float_as_uint(a), __float_as_uint(b), 0x07060302u);
}
// HW fp8 e4m3 pack: byte0 = fp8(a), byte1 = fp8(b)  (RNE, OCP on gfx950)
__device__ inline ushort cvt_pk_fp8(float a, float b) {
    unsigned r = 0;
    asm("v_cvt_pk_fp8_f32 %0, %1, %2" : "+v"(r) : "v"(a), "v"(b));
    return (ushort)r;
}
__device__ inline unsigned coarse_of(float2 v) {      // 9-bit y tile
    unsigned b = (unsigned)(v.y * 512.f); return b > 511u ? 511u : b;
}
__device__ inline unsigned fine_of(float2 v) {        // 8-bit x tile
    unsigned b = (unsigned)(v.x * 256.f); return b > 255u ? 255u : b;
}
__device__ inline int xcd_swz(int orig, int nwg) {    // bijective m204 swizzle
    const int q = nwg >> 3, r = nwg & 7;
    const int xcd = orig & 7, k = orig >> 3;
    return (xcd < r ? xcd * (q + 1) : r * (q + 1) + (xcd - r) * q) + k;
}

// ======================= K0: one-time frag-major weight prep ===============
__global__ __launch_bounds__(256) void ngp_prep_wfrag(
    const float* __restrict__ w0, const float* __restrict__ w1,
    const float* __restrict__ w2,
    unsigned long long* __restrict__ wp8, ushort* __restrict__ wp16)
{
    const int t = threadIdx.x;
    {   // fp8 W0 frags: 4 frags x 64 lanes, one per thread
        const int f = t >> 6, lane = t & 63;
        const int g4 = lane >> 4, r16 = lane & 15;
        const int nn = f * 16 + r16, k0 = 8 * g4;
        float v[8];
        #pragma unroll
        for (int j = 0; j < 8; ++j) v[j] = w0[(k0 + j) * 64 + nn];
        const unsigned long long p0 = cvt_pk_fp8(v[0], v[1]);
        const unsigned long long p1 = cvt_pk_fp8(v[2], v[3]);
        const unsigned long long p2 = cvt_pk_fp8(v[4], v[5]);
        const unsigned long long p3 = cvt_pk_fp8(v[6], v[7]);
        wp8[f * 64 + lane] = p0 | (p1 << 16) | (p2 << 32) | (p3 << 48);
    }
    for (int i = 0; i < 3; ++i) {       // bf16 frags: 10 x 64 = 640 items
        const int e = t + 256 * i;
        if (e >= 640) continue;
        const int f = e >> 6, lane = e & 63;
        const int g4 = lane >> 4, r16 = lane & 15;
        ushort v[8];
        if (f < 8) {
            const int nn = (f >> 1) * 16 + r16, k0 = (f & 1) * 32 + 8 * g4;
            #pragma unroll
            for (int j = 0; j < 8; ++j) v[j] = bf16_rn(w1[(k0 + j) * 64 + nn]);
        } else {
            const int nn = r16, k0 = (f - 8) * 32 + 8 * g4;
            #pragma unroll
            for (int j = 0; j < 8; ++j)
                v[j] = (nn < 3) ? bf16_rn(w2[(k0 + j) * 3 + nn]) : (ushort)0;
        }
        #pragma unroll
        for (int j = 0; j < 8; ++j) wp16[e * 8 + j] = v[j];
    }
}

// ======================= cooperative fused sort ============================
// Phase A: read 8192 pts/block once, local y-hist, reserve in-bucket offsets.
// grid.sync. Phase B: redundant 512-scan of totals, LDS reorder, coarse run
// writes. grid.sync. Phase C: per-stripe fine x-sort in place (L2-warm).
__global__ __launch_bounds__(1024) void ngp_sort_coop(
    const float2* __restrict__ uv, uint32_t* __restrict__ cursor,
    float2* __restrict__ suv, uint32_t* __restrict__ perm, int n)
{
    __shared__ float2       spt[P1_PTS];        // 64 KB
    __shared__ unsigned int sid[P1_PTS];        // 32 KB
    __shared__ unsigned int h[NCOARSE], lbase[NCOARSE], lcur[NCOARSE];
    __shared__ unsigned int gbase[NCOARSE], excl[NCOARSE];
    __shared__ unsigned int stot;

    const int t = threadIdx.x;
    const int b0 = blockIdx.x * P1_PTS;
    cg::grid_group grid = cg::this_grid();

    // ---- phase A ----
    if (t < NCOARSE) h[t] = 0;
    __syncthreads();
    float2 p[8]; unsigned pc[8];
    #pragma unroll
    for (int k = 0; k < 8; ++k) {
        const int i = b0 + t + k * 1024;
        if (i < n) {
            p[k] = uv[i];
            pc[k] = coarse_of(p[k]);
            atomicAdd(&h[pc[k]], 1u);
        } else pc[k] = 0xFFFFFFFFu;
    }
    __syncthreads();
    if (t < NCOARSE) gbase[t] = h[t] ? atomicAdd(&cursor[t], h[t]) : 0u;

    grid.sync();        // cursor[c] now = total count of bucket c

    // ---- phase B: global scan (redundant per block) ----
    uint32_t tot = 0;
    if (t < NCOARSE) { tot = cursor[t]; excl[t] = tot; }
    __syncthreads();
    for (int off = 1; off < NCOARSE; off <<= 1) {
        uint32_t v = 0;
        if (t < NCOARSE && t >= off) v = excl[t - off];
        __syncthreads();
        if (t < NCOARSE) excl[t] += v;
        __syncthreads();
    }
    if (t < NCOARSE) excl[t] -= tot;            // exclusive global base
    // local scan
    if (t < NCOARSE) lbase[t] = h[t];
    __syncthreads();
    for (int off = 1; off < NCOARSE; off <<= 1) {
        uint32_t v = 0;
        if (t < NCOARSE && t >= off) v = lbase[t - off];
        __syncthreads();
        if (t < NCOARSE) lbase[t] += v;
        __syncthreads();
    }
    if (t == NCOARSE - 1) stot = lbase[t];
    if (t < NCOARSE) { lbase[t] -= h[t]; lcur[t] = lbase[t]; }
    __syncthreads();
    #pragma unroll
    for (int k = 0; k < 8; ++k) {
        if (pc[k] != 0xFFFFFFFFu) {
            const uint32_t r = atomicAdd(&lcur[pc[k]], 1u);
            spt[r] = p[k];
            sid[r] = (unsigned)(b0 + t + k * 1024);
        }
    }
    __syncthreads();
    const uint32_t tt = stot;
    for (uint32_t j = t; j < tt; j += 1024) {
        const float2 v = spt[j];
        const unsigned c = coarse_of(v);
        const uint32_t d = excl[c] + gbase[c] + (j - lbase[c]);
        suv[d] = v;
        perm[d] = sid[j];
    }

    grid.sync();        // all coarse-sorted data visible

    // ---- phase C: per-stripe fine sort (in place) ----
    for (int sidx = blockIdx.x; sidx < NCOARSE; sidx += gridDim.x) {
        __syncthreads();
        const uint32_t lo = excl[sidx];
        const uint32_t hi = (sidx + 1 < NCOARSE) ? excl[sidx + 1] : (uint32_t)n;
        const uint32_t cnt = hi - lo;
        if (cnt > (uint32_t)P1_PTS) continue;   // stays coarse-sorted (correct)
        if (t < 256) h[t] = 0;
        __syncthreads();
        for (uint32_t j = t; j < cnt; j += 1024) {
            const float2 v = suv[lo + j];
            spt[j] = v; sid[j] = perm[lo + j];
            atomicAdd(&h[fine_of(v)], 1u);
        }
        __syncthreads();
        if (t < 256) lbase[t] = h[t];
        __syncthreads();
        for (int off = 1; off < 256; off <<= 1) {
            uint32_t v = 0;
            if (t < 256 && t >= off) v = lbase[t - off];
            __syncthreads();
            if (t < 256) lbase[t] += v;
            __syncthreads();
        }
        if (t < 256) lcur[t] = lbase[t] - h[t];
        __syncthreads();
        for (uint32_t j = t; j < cnt; j += 1024) {
            const float2 v = spt[j];
            const uint32_t r = atomicAdd(&lcur[fine_of(v)], 1u);
            suv[lo + r] = v;
            perm[lo + r] = sid[j];
        }
    }
}

// ============== fallback sort kernels (n too large for coop) ===============
__global__ __launch_bounds__(1024) void ngp_hist512(
    const float2* __restrict__ uv, uint32_t* __restrict__ hist, int n)
{
    __shared__ unsigned int h[NCOARSE];
    const int t = threadIdx.x;
    if (t < NCOARSE) h[t] = 0;
    __syncthreads();
    const int b0 = blockIdx.x * P1_PTS;
    #pragma unroll
    for (int k = 0; k < 8; ++k) {
        const int i = b0 + t + k * 1024;
        if (i < n) atomicAdd(&h[coarse_of(uv[i])], 1u);
    }
    __syncthreads();
    if (t < NCOARSE && h[t]) atomicAdd(&hist[t], h[t]);
}

__global__ __launch_bounds__(512) void ngp_scan512(
    const uint32_t* __restrict__ hist, uint32_t* __restrict__ base,
    uint32_t* __restrict__ cursor)
{
    __shared__ unsigned int s[NCOARSE];
    const int t = threadIdx.x;
    const uint32_t mine = hist[t];
    s[t] = mine;
    __syncthreads();
    for (int off = 1; off < NCOARSE; off <<= 1) {
        uint32_t v = (t >= off) ? s[t - off] : 0u;
        __syncthreads();
        s[t] += v;
        __syncthreads();
    }
    const uint32_t excl = s[t] - mine;
    base[t] = excl;
    cursor[t] = excl;
}

__global__ __launch_bounds__(1024) void ngp_pass1(
    const float2* __restrict__ uv, uint32_t* __restrict__ cursor,
    float2* __restrict__ suv, uint32_t* __restrict__ perm, int n)
{
    __shared__ float2       spt[P1_PTS];
    __shared__ unsigned int sid[P1_PTS];
    __shared__ unsigned int hist[NCOARSE], lbase[NCOARSE], lcur[NCOARSE], gbase[NCOARSE];
    __shared__ unsigned int stot;

    const int t = threadIdx.x;
    const int b0 = blockIdx.x * P1_PTS;
    if (t < NCOARSE) hist[t] = 0;
    __syncthreads();

    float2 p[8]; unsigned pc[8];
    #pragma unroll
    for (int k = 0; k < 8; ++k) {
        const int i = b0 + t + k * 1024;
        if (i < n) {
            p[k] = uv[i];
            pc[k] = coarse_of(p[k]);
            atomicAdd(&hist[pc[k]], 1u);
        } else pc[k] = 0xFFFFFFFFu;
    }
    __syncthreads();
    if (t < NCOARSE) lbase[t] = hist[t];
    __syncthreads();
    for (int off = 1; off < NCOARSE; off <<= 1) {
        uint32_t v = 0;
        if (t < NCOARSE && t >= off) v = lbase[t - off];
        __syncthreads();
        if (t < NCOARSE) lbase[t] += v;
        __syncthreads();
    }
    if (t < NCOARSE) {
        const uint32_t excl = lbase[t] - hist[t];
        lcur[t] = excl;
        gbase[t] = atomicAdd(&cursor[t], hist[t]);
        lbase[t] = excl;
        if (t == NCOARSE - 1) stot = excl + hist[t];
    }
    __syncthreads();
    #pragma unroll
    for (int k = 0; k < 8; ++k) {
        if (pc[k] != 0xFFFFFFFFu) {
            const uint32_t r = atomicAdd(&lcur[pc[k]], 1u);
            spt[r] = p[k];
            sid[r] = (unsigned)(b0 + t + k * 1024);
        }
    }
    __syncthreads();
    const uint32_t tot = stot;
    for (uint32_t j = t; j < tot; j += 1024) {
        const float2 v = spt[j];
        const unsigned c = coarse_of(v);
        const uint32_t d = gbase[c] + (j - lbase[c]);
        suv[d] = v;
        perm[d] = sid[j];
    }
}

__global__ __launch_bounds__(1024) void ngp_pass2(
    const uint32_t* __restrict__ basev, const uint32_t* __restrict__ histv,
    float2* __restrict__ suv, uint32_t* __restrict__ perm)
{
    __shared__ float2       spt[P2_CAP];
    __shared__ unsigned int sid[P2_CAP];
    __shared__ unsigned int hist[256], lbase[256], lcur[256];

    const int b = blockIdx.x;
    const uint32_t lo = basev[b];
    const uint32_t cnt = histv[b];
    if (cnt > P2_CAP) return;
    const int t = threadIdx.x;
    if (t < 256) hist[t] = 0;
    __syncthreads();
    for (uint32_t j = t; j < cnt; j += 1024) {
        const float2 v = suv[lo + j];
        spt[j] = v; sid[j] = perm[lo + j];
        atomicAdd(&hist[fine_of(v)], 1u);
    }
    __syncthreads();
    if (t < 256) lbase[t] = hist[t];
    __syncthreads();
    for (int off = 1; off < 256; off <<= 1) {
        uint32_t v = 0;
        if (t < 256 && t >= off) v = lbase[t - off];
        __syncthreads();
        if (t < 256) lbase[t] += v;
        __syncthreads();
    }
    if (t < 256) lcur[t] = lbase[t] - hist[t];
    __syncthreads();
    for (uint32_t j = t; j < cnt; j += 1024) {
        const float2 v = spt[j];
        const uint32_t r = atomicAdd(&lcur[fine_of(v)], 1u);
        suv[lo + r] = v;
        perm[lo + r] = sid[j];
    }
}

// ======================= K1: level-partitioned encode ======================
// 6 passes: pass 0 -> levels 0..9; pass 1 -> levels 10..11; passes 2..5 ->
// hashed levels 12..15, one 4 MB table each (owns XCD L2). Sorted pts;
// hashed even/odd 16B pair-load; XCD-banded chunks. Output: fp8 pairs x2^13.
__global__ __launch_bounds__(256) void ngp_encode2_kernel(
    const float2* __restrict__ pts,
    const float2* __restrict__ table,
    ushort* __restrict__ xt,            // [16][n] packed (fp8 f0 | fp8 f1<<8)
    NGPParams p, int n, int chunks2)
{
    const int bid = blockIdx.x;
    const int pass = bid / chunks2;
    const int chunk = xcd_swz(bid - pass * chunks2, chunks2);
    const int base = chunk * 512 + threadIdx.x;

    float2 xy[2];
    #pragma unroll
    for (int q = 0; q < 2; ++q) {
        int idx = base + q * 256;
        xy[q] = pts[idx < n ? idx : (n - 1)];
    }

    const int l0 = (pass == 0) ? 0 : (pass == 1 ? 10 : 10 + pass);
    const int l1 = (pass == 0) ? 9 : (pass == 1 ? 11 : 10 + pass);

    for (int l = l0; l <= l1; ++l) {
        const float s = p.scale[l];
        const unsigned res = p.res[l];
        const bool hashed = (p.hashed_mask >> l) & 1u;
        const float2* tl = table + ((size_t)l << LOG2T);

        #pragma unroll
        for (int q = 0; q < 2; ++q) {
            const float px = xy[q].x * s + 0.5f;
            const float py = xy[q].y * s + 0.5f;
            const float fpx = floorf(px), fpy = floorf(py);
            const float fx = px - fpx, fy = py - fpy;
            const unsigned x0 = (unsigned)fpx, y0 = (unsigned)fpy;

            float2 c00, c10, c01, c11;
            if (!hashed) {
                const unsigned b0 = x0 + y0 * res;
                const pairld q0 = *(const pairld*)(tl + b0);
                const pairld q1 = *(const pairld*)(tl + b0 + res);
                c00 = make_float2(q0.x, q0.y); c10 = make_float2(q0.z, q0.w);
                c01 = make_float2(q1.x, q1.y); c11 = make_float2(q1.z, q1.w);
            } else {
                const unsigned hy0 = y0 * PRIME_Y;
                const unsigned hy1 = (y0 + 1u) * PRIME_Y;
                if (!(x0 & 1u)) {
                    const unsigned i0 = (x0 ^ hy0) & TMASK;
                    const unsigned i2 = (x0 ^ hy1) & TMASK;
                    const pairld q0 = *(const pairld*)(tl + (i0 & ~1u));
                    const pairld q2 = *(const pairld*)(tl + (i2 & ~1u));
                    if (i0 & 1u) { c00 = make_float2(q0.z, q0.w); c10 = make_float2(q0.x, q0.y); }
                    else         { c00 = make_float2(q0.x, q0.y); c10 = make_float2(q0.z, q0.w); }
                    if (i2 & 1u) { c01 = make_float2(q2.z, q2.w); c11 = make_float2(q2.x, q2.y); }
                    else         { c01 = make_float2(q2.x, q2.y); c11 = make_float2(q2.z, q2.w); }
                } else {
                    c00 = tl[(x0 ^ hy0) & TMASK];
                    c10 = tl[((x0 + 1u) ^ hy0) & TMASK];
                    c01 = tl[(x0 ^ hy1) & TMASK];
                    c11 = tl[((x0 + 1u) ^ hy1) & TMASK];
                }
            }

            const float w00 = (1.f - fx) * (1.f - fy);
            const float w10 = fx * (1.f - fy);
            const float w01 = (1.f - fx) * fy;
            const float w11 = fx * fy;
            const float f0 = w00 * c00.x + w10 * c10.x + w01 * c01.x + w11 * c11.x;
            const float f1 = w00 * c00.y + w10 * c10.y + w01 * c01.y + w11 * c11.y;
            const ushort pk = cvt_pk_fp8(f0 * FSCALE, f1 * FSCALE);
            const int idx = base + q * 256;
            if (idx < n) xt[(size_t)l * n + idx] = pk;
        }
    }
}

// ======================= K2: barrier-free MFMA MLP (fp8 layer 0) ===========
__global__ __launch_bounds__(256, 4) void ngp_mlp_persist(
    const ushort* __restrict__ xt,
    const unsigned long long* __restrict__ wp8,
    const ushort* __restrict__ wp16,
    const uint32_t* __restrict__ perm,
    float* __restrict__ out, int n, int nchunks)
{
    __shared__ __align__(16) ushort H[256 * 72];        // [pt][k] stride 72

    const int t = threadIdx.x;
    const int lane = t & 63;
    const int w = t >> 6;
    const int g4 = lane >> 4;
    const int r16 = lane & 15;

    unsigned long long wf8[4];
    #pragma unroll
    for (int f = 0; f < 4; ++f) wf8[f] = wp8[f * 64 + lane];
    bf16x8 wf16[10];
    #pragma unroll
    for (int f = 0; f < 10; ++f)
        wf16[f] = *(const bf16x8*)(wp16 + (size_t)(f * 64 + lane) * 8);

    auto body = [&](int c) {
        const int pbase = c << 8;
        // ---------------- layer 0: fp8 MFMA --------------------------------
        #pragma unroll
        for (int mi = 0; mi < 4; ++mi) {
            const int plocal = (w * 4 + mi) * 16 + r16;
            int pg = pbase + plocal;
            pg = pg < n ? pg : n - 1;
            union { ushort s[4]; unsigned long long v; } xv;
            #pragma unroll
            for (int c4 = 0; c4 < 4; ++c4)
                xv.s[c4] = xt[(size_t)(4 * g4 + c4) * n + pg];
            f32x4 a[4];
            #pragma unroll
            for (int nt = 0; nt < 4; ++nt)
                a[nt] = __builtin_amdgcn_mfma_f32_16x16x32_fp8_fp8(
                    (long)wf8[nt], (long)xv.v, (f32x4){0.f, 0.f, 0.f, 0.f}, 0, 0, 0);
            const int pl = plocal * 72;
            #pragma unroll
            for (int nt = 0; nt < 4; ++nt) {
                const uint32_t d0 = pack_trunc(fmaxf(a[nt][1] * FUNSCALE, 0.f),
                                               fmaxf(a[nt][0] * FUNSCALE, 0.f));
                const uint32_t d1 = pack_trunc(fmaxf(a[nt][3] * FUNSCALE, 0.f),
                                               fmaxf(a[nt][2] * FUNSCALE, 0.f));
                *(uint2*)&H[pl + nt * 16 + 4 * g4] = make_uint2(d0, d1);
            }
        }
        // ---------------- layers 1+2 (wave-private H) ----------------------
        #pragma unroll
        for (int mi = 0; mi < 4; ++mi) {
            const int plocal = (w * 4 + mi) * 16 + r16;
            const int pl = plocal * 72;
            const bf16x8 bh0 = *(const bf16x8*)&H[pl + 8 * g4];
            const bf16x8 bh1 = *(const bf16x8*)&H[pl + 32 + 8 * g4];
            #pragma unroll
            for (int nt = 0; nt < 4; ++nt) {
                f32x4 acc = __builtin_amdgcn_mfma_f32_16x16x32_bf16(
                    wf16[nt * 2], bh0, (f32x4){0.f, 0.f, 0.f, 0.f}, 0, 0, 0);
                acc = __builtin_amdgcn_mfma_f32_16x16x32_bf16(
                    wf16[nt * 2 + 1], bh1, acc, 0, 0, 0);
                const uint32_t d0 = pack_trunc(fmaxf(acc[1], 0.f), fmaxf(acc[0], 0.f));
                const uint32_t d1 = pack_trunc(fmaxf(acc[3], 0.f), fmaxf(acc[2], 0.f));
                *(uint2*)&H[pl + nt * 16 + 4 * g4] = make_uint2(d0, d1);
            }
            const bf16x8 ch0 = *(const bf16x8*)&H[pl + 8 * g4];
            const bf16x8 ch1 = *(const bf16x8*)&H[pl + 32 + 8 * g4];
            f32x4 z = __builtin_amdgcn_mfma_f32_16x16x32_bf16(
                wf16[8], ch0, (f32x4){0.f, 0.f, 0.f, 0.f}, 0, 0, 0);
            z = __builtin_amdgcn_mfma_f32_16x16x32_bf16(wf16[9], ch1, z, 0, 0, 0);
            if (g4 == 0) {
                const int pgs = pbase + plocal;
                if (pgs < n) {
                    const int pg = perm ? (int)perm[pgs] : pgs;
                    #pragma unroll
                    for (int r = 0; r < 3; ++r)
                        out[(size_t)pg * 3 + r] = 1.f / (1.f + __expf(-z[r]));
                }
            }
        }
    };

    if ((gridDim.x & 7) == 0 && (nchunks & 7) == 0) {
        // XCD-banded: block's XCD reads the xt band its encode chunks wrote.
        const int cpx = nchunks >> 3;               // chunks per XCD band
        const int bpb = gridDim.x >> 3;             // blocks per band
        const int xcd = blockIdx.x & 7;
        const int local = blockIdx.x >> 3;
        for (int k = local; k < cpx; k += bpb) body(xcd * cpx + k);
    } else {
        for (int c = blockIdx.x; c < nchunks; c += gridDim.x) body(c);
    }
}

// ======================= fallback: round-1 fused kernel ====================
__global__ __launch_bounds__(256) void ngp_fused_kernel(
    const float2* __restrict__ uv,
    const float2* __restrict__ table,
    const float4* __restrict__ w0,
    const float4* __restrict__ w1,
    const float*  __restrict__ w2,
    float* __restrict__ out,
    NGPParams p, int n)
{
    __shared__ float4 sw0[512];
    __shared__ float4 sw1[1024];
    __shared__ float  sw2[192];
    const int t = threadIdx.x;
    #pragma unroll
    for (int i = 0; i < 2; i++) sw0[t + 256 * i] = w0[t + 256 * i];
    #pragma unroll
    for (int i = 0; i < 4; i++) sw1[t + 256 * i] = w1[t + 256 * i];
    if (t < 192) sw2[t] = w2[t];
    __syncthreads();
    const int gi = blockIdx.x * 256 + t;
    if (gi >= n) return;
    const float2 xy = uv[gi];
    float feat[32];
    #pragma unroll
    for (int l = 0; l < NLV; l++) {
        const float s = p.scale[l];
        const unsigned res = p.res[l];
        const float px = xy.x * s + 0.5f;
        const float py = xy.y * s + 0.5f;
        const float fpx = floorf(px), fpy = floorf(py);
        const float fx = px - fpx, fy = py - fpy;
        const unsigned x0 = (unsigned)fpx, y0 = (unsigned)fpy;
        unsigned i00, i10, i01, i11;
        if (!((p.hashed_mask >> l) & 1u)) {
            const unsigned b = x0 + y0 * res;
            i00 = b & TMASK; i10 = (b + 1u) & TMASK;
            i01 = (b + res) & TMASK; i11 = (b + res + 1u) & TMASK;
        } else {
            const unsigned hy0 = y0 * PRIME_Y;
            const unsigned hy1 = (y0 + 1u) * PRIME_Y;
            i00 = (x0 ^ hy0) & TMASK; i10 = ((x0 + 1u) ^ hy0) & TMASK;
            i01 = (x0 ^ hy1) & TMASK; i11 = ((x0 + 1u) ^ hy1) & TMASK;
        }
        const float2* tl = table + ((size_t)l << LOG2T);
        const float2 c00 = tl[i00], c10 = tl[i10], c01 = tl[i01], c11 = tl[i11];
        const float w00 = (1.f - fx) * (1.f - fy);
        const float w10 = fx * (1.f - fy);
        const float w01 = (1.f - fx) * fy;
        const float w11 = fx * fy;
        feat[2 * l]     = w00 * c00.x + w10 * c10.x + w01 * c01.x + w11 * c11.x;
        feat[2 * l + 1] = w00 * c00.y + w10 * c10.y + w01 * c01.y + w11 * c11.y;
    }
    float2 h0[32];
    #pragma unroll
    for (int j = 0; j < 32; j++) h0[j] = make_float2(0.f, 0.f);
    #pragma unroll
    for (int k = 0; k < 32; k++) {
        const float f = feat[k];
        #pragma unroll
        for (int j = 0; j < 16; j++) {
            const float4 ww = sw0[k * 16 + j];
            h0[2 * j].x = fmaf(f, ww.x, h0[2 * j].x);
            h0[2 * j].y = fmaf(f, ww.y, h0[2 * j].y);
            h0[2 * j + 1].x = fmaf(f, ww.z, h0[2 * j + 1].x);
            h0[2 * j + 1].y = fmaf(f, ww.w, h0[2 * j + 1].y);
        }
    }
    #pragma unroll
    for (int j = 0; j < 32; j++) {
        h0[j].x = fmaxf(h0[j].x, 0.f);
        h0[j].y = fmaxf(h0[j].y, 0.f);
    }
    float2 h1[32];
    #pragma unroll
    for (int j = 0; j < 32; j++) h1[j] = make_float2(0.f, 0.f);
    #pragma unroll
    for (int k = 0; k < 64; k++) {
        const float f = (k & 1) ? h0[k >> 1].y : h0[k >> 1].x;
        #pragma unroll
        for (int j = 0; j < 16; j++) {
            const float4 ww = sw1[k * 16 + j];
            h1[2 * j].x = fmaf(f, ww.x, h1[2 * j].x);
            h1[2 * j].y = fmaf(f, ww.y, h1[2 * j].y);
            h1[2 * j + 1].x = fmaf(f, ww.z, h1[2 * j + 1].x);
            h1[2 * j + 1].y = fmaf(f, ww.w, h1[2 * j + 1].y);
        }
    }
    #pragma unroll
    for (int j = 0; j < 32; j++) {
        h1[j].x = fmaxf(h1[j].x, 0.f);
        h1[j].y = fmaxf(h1[j].y, 0.f);
    }
    float z0 = 0.f, z1 = 0.f, z2 = 0.f;
    #pragma unroll
    for (int k = 0; k < 64; k++) {
        const float f = (k & 1) ? h1[k >> 1].y : h1[k >> 1].x;
        z0 = fmaf(f, sw2[3 * k + 0], z0);
        z1 = fmaf(f, sw2[3 * k + 1], z1);
        z2 = fmaf(f, sw2[3 * k + 2], z2);
    }
    out[3 * gi + 0] = 1.f / (1.f + __expf(-z0));
    out[3 * gi + 1] = 1.f / (1.f + __expf(-z1));
    out[3 * gi + 2] = 1.f / (1.f + __expf(-z2));
}

extern "C" void kernel_launch(void* const* d_in, const int* in_sizes, int n_in,
                              void* d_out, int out_size, void* d_ws, size_t ws_size,
                              hipStream_t stream) {
    const float2* uv    = (const float2*)d_in[0];
    const float2* table = (const float2*)d_in[1];
    const float*  w0f   = (const float*)d_in[2];
    const float*  w1f   = (const float*)d_in[3];
    const float*  w2f   = (const float*)d_in[4];
    float* out = (float*)d_out;

    const int n = in_sizes[0] / 2;

    NGPParams p;
    p.hashed_mask = 0;
    const double B = exp((log(2048.0) - log(16.0)) / 15.0);
    for (int l = 0; l < NLV; l++) {
        const double scale = 16.0 * pow(B, (double)l) - 1.0;
        const long long res = (long long)ceil(scale) + 1;
        p.scale[l] = (float)scale;
        p.res[l] = (unsigned)res;
        if (res * res > (long long)TSZ) p.hashed_mask |= (1u << l);
    }

    const size_t xt_bytes   = (size_t)NLV * (size_t)n * 2u;    // fp8 pairs
    const size_t wpf_bytes  = ((size_t)WPF_BYTES + 63u) & ~63ull;
    const size_t suv_bytes  = (size_t)n * 8u;
    const size_t perm_bytes = (size_t)n * 4u;
    const size_t ctl_bytes  = (size_t)NCOARSE * 4u * 3u;   // cursor | hist | base

    const size_t need_sorted = xt_bytes + wpf_bytes + suv_bytes + perm_bytes + ctl_bytes;
    const size_t need_plain  = xt_bytes + wpf_bytes;

    const int chunks  = (n + 255) / 256;
    const int chunks2 = (n + 511) / 512;

    if (ws_size < need_plain) {          // ultimate fallback
        ngp_fused_kernel<<<chunks, 256, 0, stream>>>(
            uv, table, (const float4*)w0f, (const float4*)w1f, w2f, out, p, n);
        return;
    }

    ushort* xt = (ushort*)d_ws;
    unsigned long long* wp8 = (unsigned long long*)((char*)d_ws + xt_bytes);
    ushort* wp16 = (ushort*)((char*)d_ws + xt_bytes + WP8_BYTES);
    ngp_prep_wfrag<<<1, 256, 0, stream>>>(w0f, w1f, w2f, wp8, wp16);

    const int mlp_blocks = chunks < 1024 ? chunks : 1024;

    if (ws_size < need_sorted) {         // no-sort path
        ngp_encode2_kernel<<<6 * chunks2, 256, 0, stream>>>(uv, table, xt, p, n, chunks2);
        ngp_mlp_persist<<<mlp_blocks, 256, 0, stream>>>(xt, wp8, wp16,
                                                        (const uint32_t*)nullptr, out, n, chunks);
        return;
    }

    float2*   suv    = (float2*)((char*)d_ws + xt_bytes + wpf_bytes);
    uint32_t* perm   = (uint32_t*)((char*)suv + suv_bytes);
    uint32_t* cursor = (uint32_t*)((char*)perm + perm_bytes);
    uint32_t* hist   = cursor + NCOARSE;
    uint32_t* basev  = hist + NCOARSE;

    const int p1_blocks = (n + P1_PTS - 1) / P1_PTS;

    if (p1_blocks <= 256) {
        // fused cooperative sort (1 block/CU co-resident)
        hipMemsetAsync(cursor, 0, (size_t)NCOARSE * 4u, stream);
        float2* uv_nc = (float2*)uv;
        void* args[] = { (void*)&uv_nc, (void*)&cursor, (void*)&suv,
                         (void*)&perm, (void*)&n };
        hipLaunchCooperativeKernel((void*)ngp_sort_coop, dim3(p1_blocks),
                                   dim3(1024), args, 0, stream);
    } else {
        hipMemsetAsync(hist, 0, (size_t)NCOARSE * 4u, stream);
        ngp_hist512<<<p1_blocks, 1024, 0, stream>>>(uv, hist, n);
        ngp_scan512<<<1, NCOARSE, 0, stream>>>(hist, basev, cursor);
        ngp_pass1<<<p1_blocks, 1024, 0, stream>>>(uv, cursor, suv, perm, n);
        ngp_pass2<<<NCOARSE, 1024, 0, stream>>>(basev, hist, suv, perm);
    }
    ngp_encode2_kernel<<<6 * chunks2, 256, 0, stream>>>(suv, table, xt, p, n, chunks2);
    ngp_mlp_persist<<<mlp_blocks, 256, 0, stream>>>(xt, wp8, wp16, perm, out, n, chunks);
}

// Round 14
// 172.572 us; speedup vs baseline: 1.3952x; 1.3952x over previous
//
#include <hip/hip_runtime.h>
#include <math.h>
#include <stdint.h>

#define NLV 16
#define LOG2T 19
#define TSZ (1u << LOG2T)
#define TMASK (TSZ - 1u)
#define PRIME_Y 2654435761u

// weight frags: W0 as 4 fp8-u64 frags; W1/W2 as 10 bf16x8 frags
#define WP8_BYTES  (4 * 64 * 8)      // 2048
#define WP16_BYTES (10 * 64 * 16)    // 10240
#define WPF_BYTES  (WP8_BYTES + WP16_BYTES)

#define FSCALE 8192.0f               // 2^13 feature pre-scale for fp8
#define FUNSCALE (1.0f / 8192.0f)

#define NCOARSE 512            // 9-bit y-tile
#define P1_PTS 8192            // points per pass-1 block (runs of ~16)
#define P2_CAP 5120            // max stripe size handled by pass-2 (avg 4096)

struct NGPParams {
    float scale[NLV];
    unsigned res[NLV];
    unsigned hashed_mask;
};

struct __align__(8) pairld { float x, y, z, w; };   // 16B, 8B-aligned load

typedef __attribute__((ext_vector_type(8))) short bf16x8;
typedef __attribute__((ext_vector_type(4))) float f32x4;

__device__ inline ushort bf16_rn(float f) {
    uint32_t u = __float_as_uint(f);
    return (ushort)((u + 0x7FFFu + ((u >> 16) & 1u)) >> 16);
}
__device__ inline uint32_t pack_trunc(float a, float b) {
    return __builtin_amdgcn_perm(__float_as_uint(a), __float_as_uint(b), 0x07060302u);
}
// HW fp8 e4m3 pack: byte0 = fp8(a), byte1 = fp8(b)  (RNE, OCP on gfx950)
__device__ inline ushort cvt_pk_fp8(float a, float b) {
    unsigned r = 0;
    asm("v_cvt_pk_fp8_f32 %0, %1, %2" : "+v"(r) : "v"(a), "v"(b));
    return (ushort)r;
}
__device__ inline unsigned coarse_of(float2 v) {      // 9-bit y tile
    unsigned b = (unsigned)(v.y * 512.f); return b > 511u ? 511u : b;
}
__device__ inline unsigned fine_of(float2 v) {        // 8-bit x tile
    unsigned b = (unsigned)(v.x * 256.f); return b > 255u ? 255u : b;
}
__device__ inline int xcd_swz(int orig, int nwg) {    // bijective m204 swizzle
    const int q = nwg >> 3, r = nwg & 7;
    const int xcd = orig & 7, k = orig >> 3;
    return (xcd < r ? xcd * (q + 1) : r * (q + 1) + (xcd - r) * q) + k;
}

// ======================= K0: one-time frag-major weight prep ===============
// Also zeroes the coarse histogram (stream-ordered before hist512) so no
// separate hipMemsetAsync dispatch is needed.
__global__ __launch_bounds__(256) void ngp_prep_wfrag(
    const float* __restrict__ w0, const float* __restrict__ w1,
    const float* __restrict__ w2,
    unsigned long long* __restrict__ wp8, ushort* __restrict__ wp16,
    uint32_t* __restrict__ hist)
{
    const int t = threadIdx.x;
    hist[t] = 0; hist[t + 256] = 0;
    {   // fp8 W0 frags: 4 frags x 64 lanes, one per thread
        const int f = t >> 6, lane = t & 63;
        const int g4 = lane >> 4, r16 = lane & 15;
        const int nn = f * 16 + r16, k0 = 8 * g4;
        float v[8];
        #pragma unroll
        for (int j = 0; j < 8; ++j) v[j] = w0[(k0 + j) * 64 + nn];
        const unsigned long long p0 = cvt_pk_fp8(v[0], v[1]);
        const unsigned long long p1 = cvt_pk_fp8(v[2], v[3]);
        const unsigned long long p2 = cvt_pk_fp8(v[4], v[5]);
        const unsigned long long p3 = cvt_pk_fp8(v[6], v[7]);
        wp8[f * 64 + lane] = p0 | (p1 << 16) | (p2 << 32) | (p3 << 48);
    }
    for (int i = 0; i < 3; ++i) {       // bf16 frags: 10 x 64 = 640 items
        const int e = t + 256 * i;
        if (e >= 640) continue;
        const int f = e >> 6, lane = e & 63;
        const int g4 = lane >> 4, r16 = lane & 15;
        ushort v[8];
        if (f < 8) {
            const int nn = (f >> 1) * 16 + r16, k0 = (f & 1) * 32 + 8 * g4;
            #pragma unroll
            for (int j = 0; j < 8; ++j) v[j] = bf16_rn(w1[(k0 + j) * 64 + nn]);
        } else {
            const int nn = r16, k0 = (f - 8) * 32 + 8 * g4;
            #pragma unroll
            for (int j = 0; j < 8; ++j)
                v[j] = (nn < 3) ? bf16_rn(w2[(k0 + j) * 3 + nn]) : (ushort)0;
        }
        #pragma unroll
        for (int j = 0; j < 8; ++j) wp16[e * 8 + j] = v[j];
    }
}

// ======================= sort: hist / scan / pass1 / pass2 =================
__global__ __launch_bounds__(1024) void ngp_hist512(
    const float2* __restrict__ uv, uint32_t* __restrict__ hist, int n)
{
    __shared__ unsigned int h[NCOARSE];
    const int t = threadIdx.x;
    if (t < NCOARSE) h[t] = 0;
    __syncthreads();
    const int b0 = blockIdx.x * P1_PTS;
    #pragma unroll
    for (int k = 0; k < 8; ++k) {
        const int i = b0 + t + k * 1024;
        if (i < n) atomicAdd(&h[coarse_of(uv[i])], 1u);
    }
    __syncthreads();
    if (t < NCOARSE && h[t]) atomicAdd(&hist[t], h[t]);
}

__global__ __launch_bounds__(512) void ngp_scan512(
    const uint32_t* __restrict__ hist, uint32_t* __restrict__ base,
    uint32_t* __restrict__ cursor)
{
    __shared__ unsigned int s[NCOARSE];
    const int t = threadIdx.x;
    const uint32_t mine = hist[t];
    s[t] = mine;
    __syncthreads();
    for (int off = 1; off < NCOARSE; off <<= 1) {
        uint32_t v = (t >= off) ? s[t - off] : 0u;
        __syncthreads();
        s[t] += v;
        __syncthreads();
    }
    const uint32_t excl = s[t] - mine;
    base[t] = excl;
    cursor[t] = excl;
}

// pass 1: coarse partition (y-tile). LDS rank+reorder -> run writes (~16 pts).
__global__ __launch_bounds__(1024) void ngp_pass1(
    const float2* __restrict__ uv, uint32_t* __restrict__ cursor,
    float2* __restrict__ suv, uint32_t* __restrict__ perm, int n)
{
    __shared__ float2       spt[P1_PTS];        // 64 KB
    __shared__ unsigned int sid[P1_PTS];        // 32 KB
    __shared__ unsigned int hist[NCOARSE], lbase[NCOARSE], lcur[NCOARSE], gbase[NCOARSE];
    __shared__ unsigned int stot;

    const int t = threadIdx.x;
    const int b0 = blockIdx.x * P1_PTS;
    if (t < NCOARSE) hist[t] = 0;
    __syncthreads();

    float2 p[8]; unsigned pc[8];
    #pragma unroll
    for (int k = 0; k < 8; ++k) {
        const int i = b0 + t + k * 1024;
        if (i < n) {
            p[k] = uv[i];
            pc[k] = coarse_of(p[k]);
            atomicAdd(&hist[pc[k]], 1u);
        } else pc[k] = 0xFFFFFFFFu;
    }
    __syncthreads();
    // exclusive scan of hist (Hillis-Steele on first NCOARSE threads)
    if (t < NCOARSE) lbase[t] = hist[t];
    __syncthreads();
    for (int off = 1; off < NCOARSE; off <<= 1) {
        uint32_t v = 0;
        if (t < NCOARSE && t >= off) v = lbase[t - off];
        __syncthreads();
        if (t < NCOARSE) lbase[t] += v;
        __syncthreads();
    }
    if (t < NCOARSE) {
        const uint32_t excl = lbase[t] - hist[t];
        lcur[t] = excl;
        gbase[t] = atomicAdd(&cursor[t], hist[t]);   // reserve global range
        lbase[t] = excl;
        if (t == NCOARSE - 1) stot = excl + hist[t];
    }
    __syncthreads();
    #pragma unroll
    for (int k = 0; k < 8; ++k) {
        if (pc[k] != 0xFFFFFFFFu) {
            const uint32_t r = atomicAdd(&lcur[pc[k]], 1u);
            spt[r] = p[k];
            sid[r] = (unsigned)(b0 + t + k * 1024);
        }
    }
    __syncthreads();
    const uint32_t tot = stot;
    for (uint32_t j = t; j < tot; j += 1024) {
        const float2 v = spt[j];
        const unsigned c = coarse_of(v);
        const uint32_t d = gbase[c] + (j - lbase[c]);
        suv[d] = v;
        perm[d] = sid[j];
    }
}

// pass 2: per-stripe fine sort (x-tile), in place. Stripe region is small
// (~48 KB) -> L2-resident, no write amplification.
__global__ __launch_bounds__(1024) void ngp_pass2(
    const uint32_t* __restrict__ basev, const uint32_t* __restrict__ histv,
    float2* __restrict__ suv, uint32_t* __restrict__ perm)
{
    __shared__ float2       spt[P2_CAP];        // 40 KB
    __shared__ unsigned int sid[P2_CAP];        // 20 KB
    __shared__ unsigned int hist[256], lbase[256], lcur[256];

    const int b = blockIdx.x;
    const uint32_t lo = basev[b];
    const uint32_t cnt = histv[b];
    if (cnt > P2_CAP) return;       // leave stripe coarse-sorted (still correct)
    const int t = threadIdx.x;
    if (t < 256) hist[t] = 0;
    __syncthreads();
    for (uint32_t j = t; j < cnt; j += 1024) {
        const float2 v = suv[lo + j];
        spt[j] = v; sid[j] = perm[lo + j];
        atomicAdd(&hist[fine_of(v)], 1u);
    }
    __syncthreads();
    if (t < 256) lbase[t] = hist[t];
    __syncthreads();
    for (int off = 1; off < 256; off <<= 1) {
        uint32_t v = 0;
        if (t < 256 && t >= off) v = lbase[t - off];
        __syncthreads();
        if (t < 256) lbase[t] += v;
        __syncthreads();
    }
    if (t < 256) lcur[t] = lbase[t] - hist[t];
    __syncthreads();
    for (uint32_t j = t; j < cnt; j += 1024) {
        const float2 v = spt[j];
        const uint32_t r = atomicAdd(&lcur[fine_of(v)], 1u);
        suv[lo + r] = v;
        perm[lo + r] = sid[j];
    }
}

// ======================= K1: level-partitioned encode ======================
// 6 passes: pass 0 -> levels 0..9; pass 1 -> levels 10..11; passes 2..5 ->
// hashed levels 12..15, one 4 MB table each (owns XCD L2). Sorted pts;
// hashed even/odd 16B pair-load; XCD-banded chunks. Output: fp8 pairs x2^13.
__global__ __launch_bounds__(256) void ngp_encode2_kernel(
    const float2* __restrict__ pts,
    const float2* __restrict__ table,
    ushort* __restrict__ xt,            // [16][n] packed (fp8 f0 | fp8 f1<<8)
    NGPParams p, int n, int chunks2)
{
    const int bid = blockIdx.x;
    const int pass = bid / chunks2;
    const int chunk = xcd_swz(bid - pass * chunks2, chunks2);
    const int base = chunk * 512 + threadIdx.x;

    float2 xy[2];
    #pragma unroll
    for (int q = 0; q < 2; ++q) {
        int idx = base + q * 256;
        xy[q] = pts[idx < n ? idx : (n - 1)];
    }

    const int l0 = (pass == 0) ? 0 : (pass == 1 ? 10 : 10 + pass);
    const int l1 = (pass == 0) ? 9 : (pass == 1 ? 11 : 10 + pass);

    for (int l = l0; l <= l1; ++l) {
        const float s = p.scale[l];
        const unsigned res = p.res[l];
        const bool hashed = (p.hashed_mask >> l) & 1u;
        const float2* tl = table + ((size_t)l << LOG2T);

        #pragma unroll
        for (int q = 0; q < 2; ++q) {
            const float px = xy[q].x * s + 0.5f;
            const float py = xy[q].y * s + 0.5f;
            const float fpx = floorf(px), fpy = floorf(py);
            const float fx = px - fpx, fy = py - fpy;
            const unsigned x0 = (unsigned)fpx, y0 = (unsigned)fpy;

            float2 c00, c10, c01, c11;
            if (!hashed) {
                const unsigned b0 = x0 + y0 * res;
                const pairld q0 = *(const pairld*)(tl + b0);
                const pairld q1 = *(const pairld*)(tl + b0 + res);
                c00 = make_float2(q0.x, q0.y); c10 = make_float2(q0.z, q0.w);
                c01 = make_float2(q1.x, q1.y); c11 = make_float2(q1.z, q1.w);
            } else {
                const unsigned hy0 = y0 * PRIME_Y;
                const unsigned hy1 = (y0 + 1u) * PRIME_Y;
                if (!(x0 & 1u)) {
                    const unsigned i0 = (x0 ^ hy0) & TMASK;
                    const unsigned i2 = (x0 ^ hy1) & TMASK;
                    const pairld q0 = *(const pairld*)(tl + (i0 & ~1u));
                    const pairld q2 = *(const pairld*)(tl + (i2 & ~1u));
                    if (i0 & 1u) { c00 = make_float2(q0.z, q0.w); c10 = make_float2(q0.x, q0.y); }
                    else         { c00 = make_float2(q0.x, q0.y); c10 = make_float2(q0.z, q0.w); }
                    if (i2 & 1u) { c01 = make_float2(q2.z, q2.w); c11 = make_float2(q2.x, q2.y); }
                    else         { c01 = make_float2(q2.x, q2.y); c11 = make_float2(q2.z, q2.w); }
                } else {
                    c00 = tl[(x0 ^ hy0) & TMASK];
                    c10 = tl[((x0 + 1u) ^ hy0) & TMASK];
                    c01 = tl[(x0 ^ hy1) & TMASK];
                    c11 = tl[((x0 + 1u) ^ hy1) & TMASK];
                }
            }

            const float w00 = (1.f - fx) * (1.f - fy);
            const float w10 = fx * (1.f - fy);
            const float w01 = (1.f - fx) * fy;
            const float w11 = fx * fy;
            const float f0 = w00 * c00.x + w10 * c10.x + w01 * c01.x + w11 * c11.x;
            const float f1 = w00 * c00.y + w10 * c10.y + w01 * c01.y + w11 * c11.y;
            const ushort pk = cvt_pk_fp8(f0 * FSCALE, f1 * FSCALE);
            const int idx = base + q * 256;
            if (idx < n) xt[(size_t)l * n + idx] = pk;
        }
    }
}

// ======================= K2: barrier-free MFMA MLP (fp8 layer 0) ===========
__global__ __launch_bounds__(256, 4) void ngp_mlp_persist(
    const ushort* __restrict__ xt,
    const unsigned long long* __restrict__ wp8,
    const ushort* __restrict__ wp16,
    const uint32_t* __restrict__ perm,
    float* __restrict__ out, int n, int nchunks)
{
    __shared__ __align__(16) ushort H[256 * 72];        // [pt][k] stride 72

    const int t = threadIdx.x;
    const int lane = t & 63;
    const int w = t >> 6;
    const int g4 = lane >> 4;
    const int r16 = lane & 15;

    unsigned long long wf8[4];
    #pragma unroll
    for (int f = 0; f < 4; ++f) wf8[f] = wp8[f * 64 + lane];
    bf16x8 wf16[10];
    #pragma unroll
    for (int f = 0; f < 10; ++f)
        wf16[f] = *(const bf16x8*)(wp16 + (size_t)(f * 64 + lane) * 8);

    for (int c = blockIdx.x; c < nchunks; c += gridDim.x) {
        const int pbase = c << 8;
        // ---------------- layer 0: fp8 MFMA --------------------------------
        #pragma unroll
        for (int mi = 0; mi < 4; ++mi) {
            const int plocal = (w * 4 + mi) * 16 + r16;
            int pg = pbase + plocal;
            pg = pg < n ? pg : n - 1;
            union { ushort s[4]; unsigned long long v; } xv;
            #pragma unroll
            for (int c4 = 0; c4 < 4; ++c4)
                xv.s[c4] = xt[(size_t)(4 * g4 + c4) * n + pg];
            f32x4 a[4];
            #pragma unroll
            for (int nt = 0; nt < 4; ++nt)
                a[nt] = __builtin_amdgcn_mfma_f32_16x16x32_fp8_fp8(
                    (long)wf8[nt], (long)xv.v, (f32x4){0.f, 0.f, 0.f, 0.f}, 0, 0, 0);
            const int pl = plocal * 72;
            #pragma unroll
            for (int nt = 0; nt < 4; ++nt) {
                const uint32_t d0 = pack_trunc(fmaxf(a[nt][1] * FUNSCALE, 0.f),
                                               fmaxf(a[nt][0] * FUNSCALE, 0.f));
                const uint32_t d1 = pack_trunc(fmaxf(a[nt][3] * FUNSCALE, 0.f),
                                               fmaxf(a[nt][2] * FUNSCALE, 0.f));
                *(uint2*)&H[pl + nt * 16 + 4 * g4] = make_uint2(d0, d1);
            }
        }
        // ---------------- layers 1+2 (wave-private H) ----------------------
        #pragma unroll
        for (int mi = 0; mi < 4; ++mi) {
            const int plocal = (w * 4 + mi) * 16 + r16;
            const int pl = plocal * 72;
            const bf16x8 bh0 = *(const bf16x8*)&H[pl + 8 * g4];
            const bf16x8 bh1 = *(const bf16x8*)&H[pl + 32 + 8 * g4];
            #pragma unroll
            for (int nt = 0; nt < 4; ++nt) {
                f32x4 acc = __builtin_amdgcn_mfma_f32_16x16x32_bf16(
                    wf16[nt * 2], bh0, (f32x4){0.f, 0.f, 0.f, 0.f}, 0, 0, 0);
                acc = __builtin_amdgcn_mfma_f32_16x16x32_bf16(
                    wf16[nt * 2 + 1], bh1, acc, 0, 0, 0);
                const uint32_t d0 = pack_trunc(fmaxf(acc[1], 0.f), fmaxf(acc[0], 0.f));
                const uint32_t d1 = pack_trunc(fmaxf(acc[3], 0.f), fmaxf(acc[2], 0.f));
                *(uint2*)&H[pl + nt * 16 + 4 * g4] = make_uint2(d0, d1);
            }
            const bf16x8 ch0 = *(const bf16x8*)&H[pl + 8 * g4];
            const bf16x8 ch1 = *(const bf16x8*)&H[pl + 32 + 8 * g4];
            f32x4 z = __builtin_amdgcn_mfma_f32_16x16x32_bf16(
                wf16[8], ch0, (f32x4){0.f, 0.f, 0.f, 0.f}, 0, 0, 0);
            z = __builtin_amdgcn_mfma_f32_16x16x32_bf16(wf16[9], ch1, z, 0, 0, 0);
            if (g4 == 0) {
                const int pgs = pbase + plocal;
                if (pgs < n) {
                    const int pg = perm ? (int)perm[pgs] : pgs;
                    #pragma unroll
                    for (int r = 0; r < 3; ++r)
                        out[(size_t)pg * 3 + r] = 1.f / (1.f + __expf(-z[r]));
                }
            }
        }
    }
}

// ======================= fallback: round-1 fused kernel ====================
__global__ __launch_bounds__(256) void ngp_fused_kernel(
    const float2* __restrict__ uv,
    const float2* __restrict__ table,
    const float4* __restrict__ w0,
    const float4* __restrict__ w1,
    const float*  __restrict__ w2,
    float* __restrict__ out,
    NGPParams p, int n)
{
    __shared__ float4 sw0[512];
    __shared__ float4 sw1[1024];
    __shared__ float  sw2[192];
    const int t = threadIdx.x;
    #pragma unroll
    for (int i = 0; i < 2; i++) sw0[t + 256 * i] = w0[t + 256 * i];
    #pragma unroll
    for (int i = 0; i < 4; i++) sw1[t + 256 * i] = w1[t + 256 * i];
    if (t < 192) sw2[t] = w2[t];
    __syncthreads();
    const int gi = blockIdx.x * 256 + t;
    if (gi >= n) return;
    const float2 xy = uv[gi];
    float feat[32];
    #pragma unroll
    for (int l = 0; l < NLV; l++) {
        const float s = p.scale[l];
        const unsigned res = p.res[l];
        const float px = xy.x * s + 0.5f;
        const float py = xy.y * s + 0.5f;
        const float fpx = floorf(px), fpy = floorf(py);
        const float fx = px - fpx, fy = py - fpy;
        const unsigned x0 = (unsigned)fpx, y0 = (unsigned)fpy;
        unsigned i00, i10, i01, i11;
        if (!((p.hashed_mask >> l) & 1u)) {
            const unsigned b = x0 + y0 * res;
            i00 = b & TMASK; i10 = (b + 1u) & TMASK;
            i01 = (b + res) & TMASK; i11 = (b + res + 1u) & TMASK;
        } else {
            const unsigned hy0 = y0 * PRIME_Y;
            const unsigned hy1 = (y0 + 1u) * PRIME_Y;
            i00 = (x0 ^ hy0) & TMASK; i10 = ((x0 + 1u) ^ hy0) & TMASK;
            i01 = (x0 ^ hy1) & TMASK; i11 = ((x0 + 1u) ^ hy1) & TMASK;
        }
        const float2* tl = table + ((size_t)l << LOG2T);
        const float2 c00 = tl[i00], c10 = tl[i10], c01 = tl[i01], c11 = tl[i11];
        const float w00 = (1.f - fx) * (1.f - fy);
        const float w10 = fx * (1.f - fy);
        const float w01 = (1.f - fx) * fy;
        const float w11 = fx * fy;
        feat[2 * l]     = w00 * c00.x + w10 * c10.x + w01 * c01.x + w11 * c11.x;
        feat[2 * l + 1] = w00 * c00.y + w10 * c10.y + w01 * c01.y + w11 * c11.y;
    }
    float2 h0[32];
    #pragma unroll
    for (int j = 0; j < 32; j++) h0[j] = make_float2(0.f, 0.f);
    #pragma unroll
    for (int k = 0; k < 32; k++) {
        const float f = feat[k];
        #pragma unroll
        for (int j = 0; j < 16; j++) {
            const float4 ww = sw0[k * 16 + j];
            h0[2 * j].x = fmaf(f, ww.x, h0[2 * j].x);
            h0[2 * j].y = fmaf(f, ww.y, h0[2 * j].y);
            h0[2 * j + 1].x = fmaf(f, ww.z, h0[2 * j + 1].x);
            h0[2 * j + 1].y = fmaf(f, ww.w, h0[2 * j + 1].y);
        }
    }
    #pragma unroll
    for (int j = 0; j < 32; j++) {
        h0[j].x = fmaxf(h0[j].x, 0.f);
        h0[j].y = fmaxf(h0[j].y, 0.f);
    }
    float2 h1[32];
    #pragma unroll
    for (int j = 0; j < 32; j++) h1[j] = make_float2(0.f, 0.f);
    #pragma unroll
    for (int k = 0; k < 64; k++) {
        const float f = (k & 1) ? h0[k >> 1].y : h0[k >> 1].x;
        #pragma unroll
        for (int j = 0; j < 16; j++) {
            const float4 ww = sw1[k * 16 + j];
            h1[2 * j].x = fmaf(f, ww.x, h1[2 * j].x);
            h1[2 * j].y = fmaf(f, ww.y, h1[2 * j].y);
            h1[2 * j + 1].x = fmaf(f, ww.z, h1[2 * j + 1].x);
            h1[2 * j + 1].y = fmaf(f, ww.w, h1[2 * j + 1].y);
        }
    }
    #pragma unroll
    for (int j = 0; j < 32; j++) {
        h1[j].x = fmaxf(h1[j].x, 0.f);
        h1[j].y = fmaxf(h1[j].y, 0.f);
    }
    float z0 = 0.f, z1 = 0.f, z2 = 0.f;
    #pragma unroll
    for (int k = 0; k < 64; k++) {
        const float f = (k & 1) ? h1[k >> 1].y : h1[k >> 1].x;
        z0 = fmaf(f, sw2[3 * k + 0], z0);
        z1 = fmaf(f, sw2[3 * k + 1], z1);
        z2 = fmaf(f, sw2[3 * k + 2], z2);
    }
    out[3 * gi + 0] = 1.f / (1.f + __expf(-z0));
    out[3 * gi + 1] = 1.f / (1.f + __expf(-z1));
    out[3 * gi + 2] = 1.f / (1.f + __expf(-z2));
}

extern "C" void kernel_launch(void* const* d_in, const int* in_sizes, int n_in,
                              void* d_out, int out_size, void* d_ws, size_t ws_size,
                              hipStream_t stream) {
    const float2* uv    = (const float2*)d_in[0];
    const float2* table = (const float2*)d_in[1];
    const float*  w0f   = (const float*)d_in[2];
    const float*  w1f   = (const float*)d_in[3];
    const float*  w2f   = (const float*)d_in[4];
    float* out = (float*)d_out;

    const int n = in_sizes[0] / 2;

    NGPParams p;
    p.hashed_mask = 0;
    const double B = exp((log(2048.0) - log(16.0)) / 15.0);
    for (int l = 0; l < NLV; l++) {
        const double scale = 16.0 * pow(B, (double)l) - 1.0;
        const long long res = (long long)ceil(scale) + 1;
        p.scale[l] = (float)scale;
        p.res[l] = (unsigned)res;
        if (res * res > (long long)TSZ) p.hashed_mask |= (1u << l);
    }

    const size_t xt_bytes   = (size_t)NLV * (size_t)n * 2u;    // fp8 pairs
    const size_t wpf_bytes  = ((size_t)WPF_BYTES + 63u) & ~63ull;
    const size_t suv_bytes  = (size_t)n * 8u;
    const size_t perm_bytes = (size_t)n * 4u;
    const size_t ctl_bytes  = (size_t)NCOARSE * 4u * 3u;   // hist | base | cursor

    const size_t need_sorted = xt_bytes + wpf_bytes + suv_bytes + perm_bytes + ctl_bytes;
    const size_t need_plain  = xt_bytes + wpf_bytes;

    const int chunks  = (n + 255) / 256;
    const int chunks2 = (n + 511) / 512;

    if (ws_size < need_plain) {          // ultimate fallback
        ngp_fused_kernel<<<chunks, 256, 0, stream>>>(
            uv, table, (const float4*)w0f, (const float4*)w1f, w2f, out, p, n);
        return;
    }

    ushort* xt = (ushort*)d_ws;
    unsigned long long* wp8 = (unsigned long long*)((char*)d_ws + xt_bytes);
    ushort* wp16 = (ushort*)((char*)d_ws + xt_bytes + WP8_BYTES);

    float2*   suv    = (float2*)((char*)d_ws + xt_bytes + wpf_bytes);
    uint32_t* perm   = (uint32_t*)((char*)suv + suv_bytes);
    uint32_t* hist   = (uint32_t*)((char*)perm + perm_bytes);
    uint32_t* basev  = hist + NCOARSE;
    uint32_t* cursor = basev + NCOARSE;

    const int mlp_blocks = chunks < 1024 ? chunks : 1024;

    if (ws_size < need_sorted) {         // no-sort path
        ngp_prep_wfrag<<<1, 256, 0, stream>>>(w0f, w1f, w2f, wp8, wp16,
                                              (uint32_t*)((char*)d_ws + xt_bytes + WPF_BYTES - 2048));
        ngp_encode2_kernel<<<6 * chunks2, 256, 0, stream>>>(uv, table, xt, p, n, chunks2);
        ngp_mlp_persist<<<mlp_blocks, 256, 0, stream>>>(xt, wp8, wp16,
                                                        (const uint32_t*)nullptr, out, n, chunks);
        return;
    }

    const int p1_blocks = (n + P1_PTS - 1) / P1_PTS;

    ngp_prep_wfrag<<<1, 256, 0, stream>>>(w0f, w1f, w2f, wp8, wp16, hist);
    ngp_hist512<<<p1_blocks, 1024, 0, stream>>>(uv, hist, n);
    ngp_scan512<<<1, NCOARSE, 0, stream>>>(hist, basev, cursor);
    ngp_pass1<<<p1_blocks, 1024, 0, stream>>>(uv, cursor, suv, perm, n);
    ngp_pass2<<<NCOARSE, 1024, 0, stream>>>(basev, hist, suv, perm);
    ngp_encode2_kernel<<<6 * chunks2, 256, 0, stream>>>(suv, table, xt, p, n, chunks2);
    ngp_mlp_persist<<<mlp_blocks, 256, 0, stream>>>(xt, wp8, wp16, perm, out, n, chunks);
}

// Round 15
// 170.395 us; speedup vs baseline: 1.4130x; 1.0128x over previous
//
#include <hip/hip_runtime.h>
#include <math.h>
#include <stdint.h>

#define NLV 16
#define LOG2T 19
#define TSZ (1u << LOG2T)
#define TMASK (TSZ - 1u)
#define PRIME_Y 2654435761u

// weight frags: W0 as 4 fp8-u64 frags; W1/W2 as 10 bf16x8 frags
#define WP8_BYTES  (4 * 64 * 8)      // 2048
#define WP16_BYTES (10 * 64 * 16)    // 10240
#define WPF_BYTES  (WP8_BYTES + WP16_BYTES)

#define FSCALE 8192.0f               // 2^13 feature pre-scale for fp8
#define FUNSCALE (1.0f / 8192.0f)

#define NCOARSE 512            // 9-bit y-tile
#define P1_PTS 8192            // points per pass-1 block (runs of ~16)
#define P2_CAP 5120            // max stripe size handled by pass-2 (avg 4096)

struct NGPParams {
    float scale[NLV];
    unsigned res[NLV];
    unsigned hashed_mask;
};

struct __align__(8) pairld { float x, y, z, w; };   // 16B, 8B-aligned load

typedef __attribute__((ext_vector_type(8))) short bf16x8;
typedef __attribute__((ext_vector_type(4))) float f32x4;

__device__ inline ushort bf16_rn(float f) {
    uint32_t u = __float_as_uint(f);
    return (ushort)((u + 0x7FFFu + ((u >> 16) & 1u)) >> 16);
}
__device__ inline uint32_t pack_trunc(float a, float b) {
    return __builtin_amdgcn_perm(__float_as_uint(a), __float_as_uint(b), 0x07060302u);
}
// HW fp8 e4m3 pack: byte0 = fp8(a), byte1 = fp8(b)  (RNE, OCP on gfx950)
__device__ inline ushort cvt_pk_fp8(float a, float b) {
    unsigned r = 0;
    asm("v_cvt_pk_fp8_f32 %0, %1, %2" : "+v"(r) : "v"(a), "v"(b));
    return (ushort)r;
}
__device__ inline unsigned coarse_of(float2 v) {      // 9-bit y tile
    unsigned b = (unsigned)(v.y * 512.f); return b > 511u ? 511u : b;
}
__device__ inline unsigned fine_of(float2 v) {        // 8-bit x tile
    unsigned b = (unsigned)(v.x * 256.f); return b > 255u ? 255u : b;
}
__device__ inline int xcd_swz(int orig, int nwg) {    // bijective m204 swizzle
    const int q = nwg >> 3, r = nwg & 7;
    const int xcd = orig & 7, k = orig >> 3;
    return (xcd < r ? xcd * (q + 1) : r * (q + 1) + (xcd - r) * q) + k;
}

// ======================= K0: one-time frag-major weight prep ===============
// Also zeroes the coarse histogram + cursor (stream-ordered before hist512).
__global__ __launch_bounds__(256) void ngp_prep_wfrag(
    const float* __restrict__ w0, const float* __restrict__ w1,
    const float* __restrict__ w2,
    unsigned long long* __restrict__ wp8, ushort* __restrict__ wp16,
    uint32_t* __restrict__ ctl)     // [hist 512 | cursor 512] or nullptr
{
    const int t = threadIdx.x;
    if (ctl) { ctl[t] = 0; ctl[t + 256] = 0; ctl[t + 512] = 0; ctl[t + 768] = 0; }
    {   // fp8 W0 frags: 4 frags x 64 lanes, one per thread
        const int f = t >> 6, lane = t & 63;
        const int g4 = lane >> 4, r16 = lane & 15;
        const int nn = f * 16 + r16, k0 = 8 * g4;
        float v[8];
        #pragma unroll
        for (int j = 0; j < 8; ++j) v[j] = w0[(k0 + j) * 64 + nn];
        const unsigned long long p0 = cvt_pk_fp8(v[0], v[1]);
        const unsigned long long p1 = cvt_pk_fp8(v[2], v[3]);
        const unsigned long long p2 = cvt_pk_fp8(v[4], v[5]);
        const unsigned long long p3 = cvt_pk_fp8(v[6], v[7]);
        wp8[f * 64 + lane] = p0 | (p1 << 16) | (p2 << 32) | (p3 << 48);
    }
    for (int i = 0; i < 3; ++i) {       // bf16 frags: 10 x 64 = 640 items
        const int e = t + 256 * i;
        if (e >= 640) continue;
        const int f = e >> 6, lane = e & 63;
        const int g4 = lane >> 4, r16 = lane & 15;
        ushort v[8];
        if (f < 8) {
            const int nn = (f >> 1) * 16 + r16, k0 = (f & 1) * 32 + 8 * g4;
            #pragma unroll
            for (int j = 0; j < 8; ++j) v[j] = bf16_rn(w1[(k0 + j) * 64 + nn]);
        } else {
            const int nn = r16, k0 = (f - 8) * 32 + 8 * g4;
            #pragma unroll
            for (int j = 0; j < 8; ++j)
                v[j] = (nn < 3) ? bf16_rn(w2[(k0 + j) * 3 + nn]) : (ushort)0;
        }
        #pragma unroll
        for (int j = 0; j < 8; ++j) wp16[e * 8 + j] = v[j];
    }
}

// ======================= sort: hist / pass1 / pass2 ========================
__global__ __launch_bounds__(1024) void ngp_hist512(
    const float2* __restrict__ uv, uint32_t* __restrict__ hist, int n)
{
    __shared__ unsigned int h[NCOARSE];
    const int t = threadIdx.x;
    if (t < NCOARSE) h[t] = 0;
    __syncthreads();
    const int b0 = blockIdx.x * P1_PTS;
    #pragma unroll
    for (int k = 0; k < 8; ++k) {
        const int i = b0 + t + k * 1024;
        if (i < n) atomicAdd(&h[coarse_of(uv[i])], 1u);
    }
    __syncthreads();
    if (t < NCOARSE && h[t]) atomicAdd(&hist[t], h[t]);
}

// pass 1: coarse partition (y-tile). Recomputes the global 512-scan from
// hist per block (L2-hot, fused into the local scan's barrier loop);
// reserves its range via cursor (zero-based). LDS reorder -> run writes.
__global__ __launch_bounds__(1024) void ngp_pass1(
    const float2* __restrict__ uv, const uint32_t* __restrict__ ghist,
    uint32_t* __restrict__ cursor,
    float2* __restrict__ suv, uint32_t* __restrict__ perm, int n)
{
    __shared__ float2       spt[P1_PTS];        // 64 KB
    __shared__ unsigned int sid[P1_PTS];        // 32 KB
    __shared__ unsigned int h[NCOARSE], lbase[NCOARSE], lcur[NCOARSE];
    __shared__ unsigned int gex[NCOARSE], gbase[NCOARSE];
    __shared__ unsigned int stot;

    const int t = threadIdx.x;
    const int b0 = blockIdx.x * P1_PTS;
    if (t < NCOARSE) h[t] = 0;
    __syncthreads();

    float2 p[8]; unsigned pc[8];
    #pragma unroll
    for (int k = 0; k < 8; ++k) {
        const int i = b0 + t + k * 1024;
        if (i < n) {
            p[k] = uv[i];
            pc[k] = coarse_of(p[k]);
            atomicAdd(&h[pc[k]], 1u);
        } else pc[k] = 0xFFFFFFFFu;
    }
    __syncthreads();
    // fused Hillis-Steele: global scan of ghist + local scan of h
    unsigned mg = 0, ml = 0;
    if (t < NCOARSE) {
        mg = ghist[t]; ml = h[t];
        gex[t] = mg; lbase[t] = ml;
    }
    __syncthreads();
    for (int off = 1; off < NCOARSE; off <<= 1) {
        unsigned vg = 0, vl = 0;
        if (t < NCOARSE && t >= off) { vg = gex[t - off]; vl = lbase[t - off]; }
        __syncthreads();
        if (t < NCOARSE) { gex[t] += vg; lbase[t] += vl; }
        __syncthreads();
    }
    if (t < NCOARSE) {
        const unsigned lex = lbase[t] - ml;          // local exclusive
        lcur[t] = lex;
        gbase[t] = (gex[t] - mg) + atomicAdd(&cursor[t], ml);
        lbase[t] = lex;
        if (t == NCOARSE - 1) stot = lex + ml;
    }
    __syncthreads();
    #pragma unroll
    for (int k = 0; k < 8; ++k) {
        if (pc[k] != 0xFFFFFFFFu) {
            const uint32_t r = atomicAdd(&lcur[pc[k]], 1u);
            spt[r] = p[k];
            sid[r] = (unsigned)(b0 + t + k * 1024);
        }
    }
    __syncthreads();
    const uint32_t tot = stot;
    for (uint32_t j = t; j < tot; j += 1024) {
        const float2 v = spt[j];
        const unsigned c = coarse_of(v);
        const uint32_t d = gbase[c] + (j - lbase[c]);
        suv[d] = v;
        perm[d] = sid[j];
    }
}

// pass 2: per-stripe fine sort (x-tile), in place. Recomputes the global
// scan from hist per block for its stripe base. Stripe is L2-resident.
__global__ __launch_bounds__(1024) void ngp_pass2(
    const uint32_t* __restrict__ ghist,
    float2* __restrict__ suv, uint32_t* __restrict__ perm)
{
    __shared__ float2       spt[P2_CAP];        // 40 KB
    __shared__ unsigned int sid[P2_CAP];        // 20 KB
    __shared__ unsigned int gex[NCOARSE];
    __shared__ unsigned int h[256], lbase[256], lcur[256];
    __shared__ unsigned int s_lo, s_cnt;

    const int t = threadIdx.x;
    const int b = blockIdx.x;
    unsigned mine = 0;
    if (t < NCOARSE) { mine = ghist[t]; gex[t] = mine; }
    __syncthreads();
    for (int off = 1; off < NCOARSE; off <<= 1) {
        unsigned v = 0;
        if (t < NCOARSE && t >= off) v = gex[t - off];
        __syncthreads();
        if (t < NCOARSE) gex[t] += v;
        __syncthreads();
    }
    if (t == b) { s_cnt = mine; s_lo = gex[b] - mine; }   // b < 512 <= blockDim
    __syncthreads();
    const uint32_t lo = s_lo;
    const uint32_t cnt = s_cnt;
    if (cnt > P2_CAP) return;       // leave stripe coarse-sorted (still correct)
    if (t < 256) h[t] = 0;
    __syncthreads();
    for (uint32_t j = t; j < cnt; j += 1024) {
        const float2 v = suv[lo + j];
        spt[j] = v; sid[j] = perm[lo + j];
        atomicAdd(&h[fine_of(v)], 1u);
    }
    __syncthreads();
    if (t < 256) lbase[t] = h[t];
    __syncthreads();
    for (int off = 1; off < 256; off <<= 1) {
        uint32_t v = 0;
        if (t < 256 && t >= off) v = lbase[t - off];
        __syncthreads();
        if (t < 256) lbase[t] += v;
        __syncthreads();
    }
    if (t < 256) lcur[t] = lbase[t] - h[t];
    __syncthreads();
    for (uint32_t j = t; j < cnt; j += 1024) {
        const float2 v = spt[j];
        const uint32_t r = atomicAdd(&lcur[fine_of(v)], 1u);
        suv[lo + r] = v;
        perm[lo + r] = sid[j];
    }
}

// ======================= K1: level-partitioned encode ======================
// 5 passes: pass 0 -> dense levels 0..11 (banded per-XCD WS ~0.65 MB);
// passes 1..4 -> hashed levels 12..15, one 4 MB table each (owns XCD L2).
// Sorted pts; hashed even/odd 16B pair-load; XCD-banded chunks.
// Output: fp8 pairs x2^13.
__global__ __launch_bounds__(256) void ngp_encode2_kernel(
    const float2* __restrict__ pts,
    const float2* __restrict__ table,
    ushort* __restrict__ xt,            // [16][n] packed (fp8 f0 | fp8 f1<<8)
    NGPParams p, int n, int chunks2)
{
    const int bid = blockIdx.x;
    const int pass = bid / chunks2;
    const int chunk = xcd_swz(bid - pass * chunks2, chunks2);
    const int base = chunk * 512 + threadIdx.x;

    float2 xy[2];
    #pragma unroll
    for (int q = 0; q < 2; ++q) {
        int idx = base + q * 256;
        xy[q] = pts[idx < n ? idx : (n - 1)];
    }

    const int l0 = (pass == 0) ? 0 : 11 + pass;
    const int l1 = (pass == 0) ? 11 : 11 + pass;

    for (int l = l0; l <= l1; ++l) {
        const float s = p.scale[l];
        const unsigned res = p.res[l];
        const bool hashed = (p.hashed_mask >> l) & 1u;
        const float2* tl = table + ((size_t)l << LOG2T);

        #pragma unroll
        for (int q = 0; q < 2; ++q) {
            const float px = xy[q].x * s + 0.5f;
            const float py = xy[q].y * s + 0.5f;
            const float fpx = floorf(px), fpy = floorf(py);
            const float fx = px - fpx, fy = py - fpy;
            const unsigned x0 = (unsigned)fpx, y0 = (unsigned)fpy;

            float2 c00, c10, c01, c11;
            if (!hashed) {
                // dense: indices never wrap (res^2 < T); corners x-adjacent.
                const unsigned b0 = x0 + y0 * res;
                const pairld q0 = *(const pairld*)(tl + b0);
                const pairld q1 = *(const pairld*)(tl + b0 + res);
                c00 = make_float2(q0.x, q0.y); c10 = make_float2(q0.z, q0.w);
                c01 = make_float2(q1.x, q1.y); c11 = make_float2(q1.z, q1.w);
            } else {
                const unsigned hy0 = y0 * PRIME_Y;
                const unsigned hy1 = (y0 + 1u) * PRIME_Y;
                if (!(x0 & 1u)) {
                    // x0 even: (x0^h) and ((x0+1)^h) differ only in bit 0.
                    const unsigned i0 = (x0 ^ hy0) & TMASK;
                    const unsigned i2 = (x0 ^ hy1) & TMASK;
                    const pairld q0 = *(const pairld*)(tl + (i0 & ~1u));
                    const pairld q2 = *(const pairld*)(tl + (i2 & ~1u));
                    if (i0 & 1u) { c00 = make_float2(q0.z, q0.w); c10 = make_float2(q0.x, q0.y); }
                    else         { c00 = make_float2(q0.x, q0.y); c10 = make_float2(q0.z, q0.w); }
                    if (i2 & 1u) { c01 = make_float2(q2.z, q2.w); c11 = make_float2(q2.x, q2.y); }
                    else         { c01 = make_float2(q2.x, q2.y); c11 = make_float2(q2.z, q2.w); }
                } else {
                    c00 = tl[(x0 ^ hy0) & TMASK];
                    c10 = tl[((x0 + 1u) ^ hy0) & TMASK];
                    c01 = tl[(x0 ^ hy1) & TMASK];
                    c11 = tl[((x0 + 1u) ^ hy1) & TMASK];
                }
            }

            const float w00 = (1.f - fx) * (1.f - fy);
            const float w10 = fx * (1.f - fy);
            const float w01 = (1.f - fx) * fy;
            const float w11 = fx * fy;
            const float f0 = w00 * c00.x + w10 * c10.x + w01 * c01.x + w11 * c11.x;
            const float f1 = w00 * c00.y + w10 * c10.y + w01 * c01.y + w11 * c11.y;
            const ushort pk = cvt_pk_fp8(f0 * FSCALE, f1 * FSCALE);
            const int idx = base + q * 256;
            if (idx < n) xt[(size_t)l * n + idx] = pk;
        }
    }
}

// ======================= K2: barrier-free MFMA MLP (fp8 layer 0) ===========
__global__ __launch_bounds__(256, 4) void ngp_mlp_persist(
    const ushort* __restrict__ xt,
    const unsigned long long* __restrict__ wp8,
    const ushort* __restrict__ wp16,
    const uint32_t* __restrict__ perm,
    float* __restrict__ out, int n, int nchunks)
{
    __shared__ __align__(16) ushort H[256 * 72];        // [pt][k] stride 72

    const int t = threadIdx.x;
    const int lane = t & 63;
    const int w = t >> 6;
    const int g4 = lane >> 4;
    const int r16 = lane & 15;

    unsigned long long wf8[4];
    #pragma unroll
    for (int f = 0; f < 4; ++f) wf8[f] = wp8[f * 64 + lane];
    bf16x8 wf16[10];
    #pragma unroll
    for (int f = 0; f < 10; ++f)
        wf16[f] = *(const bf16x8*)(wp16 + (size_t)(f * 64 + lane) * 8);

    for (int c = blockIdx.x; c < nchunks; c += gridDim.x) {
        const int pbase = c << 8;
        // ---------------- layer 0: fp8 MFMA --------------------------------
        #pragma unroll
        for (int mi = 0; mi < 4; ++mi) {
            const int plocal = (w * 4 + mi) * 16 + r16;
            int pg = pbase + plocal;
            pg = pg < n ? pg : n - 1;
            union { ushort s[4]; unsigned long long v; } xv;
            #pragma unroll
            for (int c4 = 0; c4 < 4; ++c4)
                xv.s[c4] = xt[(size_t)(4 * g4 + c4) * n + pg];
            f32x4 a[4];
            #pragma unroll
            for (int nt = 0; nt < 4; ++nt)
                a[nt] = __builtin_amdgcn_mfma_f32_16x16x32_fp8_fp8(
                    (long)wf8[nt], (long)xv.v, (f32x4){0.f, 0.f, 0.f, 0.f}, 0, 0, 0);
            const int pl = plocal * 72;
            #pragma unroll
            for (int nt = 0; nt < 4; ++nt) {
                const uint32_t d0 = pack_trunc(fmaxf(a[nt][1] * FUNSCALE, 0.f),
                                               fmaxf(a[nt][0] * FUNSCALE, 0.f));
                const uint32_t d1 = pack_trunc(fmaxf(a[nt][3] * FUNSCALE, 0.f),
                                               fmaxf(a[nt][2] * FUNSCALE, 0.f));
                *(uint2*)&H[pl + nt * 16 + 4 * g4] = make_uint2(d0, d1);
            }
        }
        // ---------------- layers 1+2 (wave-private H) ----------------------
        #pragma unroll
        for (int mi = 0; mi < 4; ++mi) {
            const int plocal = (w * 4 + mi) * 16 + r16;
            const int pl = plocal * 72;
            const bf16x8 bh0 = *(const bf16x8*)&H[pl + 8 * g4];
            const bf16x8 bh1 = *(const bf16x8*)&H[pl + 32 + 8 * g4];
            #pragma unroll
            for (int nt = 0; nt < 4; ++nt) {
                f32x4 acc = __builtin_amdgcn_mfma_f32_16x16x32_bf16(
                    wf16[nt * 2], bh0, (f32x4){0.f, 0.f, 0.f, 0.f}, 0, 0, 0);
                acc = __builtin_amdgcn_mfma_f32_16x16x32_bf16(
                    wf16[nt * 2 + 1], bh1, acc, 0, 0, 0);
                const uint32_t d0 = pack_trunc(fmaxf(acc[1], 0.f), fmaxf(acc[0], 0.f));
                const uint32_t d1 = pack_trunc(fmaxf(acc[3], 0.f), fmaxf(acc[2], 0.f));
                *(uint2*)&H[pl + nt * 16 + 4 * g4] = make_uint2(d0, d1);
            }
            const bf16x8 ch0 = *(const bf16x8*)&H[pl + 8 * g4];
            const bf16x8 ch1 = *(const bf16x8*)&H[pl + 32 + 8 * g4];
            f32x4 z = __builtin_amdgcn_mfma_f32_16x16x32_bf16(
                wf16[8], ch0, (f32x4){0.f, 0.f, 0.f, 0.f}, 0, 0, 0);
            z = __builtin_amdgcn_mfma_f32_16x16x32_bf16(wf16[9], ch1, z, 0, 0, 0);
            if (g4 == 0) {
                const int pgs = pbase + plocal;
                if (pgs < n) {
                    const int pg = perm ? (int)perm[pgs] : pgs;
                    #pragma unroll
                    for (int r = 0; r < 3; ++r)
                        out[(size_t)pg * 3 + r] = 1.f / (1.f + __expf(-z[r]));
                }
            }
        }
    }
}

// ======================= fallback: round-1 fused kernel ====================
__global__ __launch_bounds__(256) void ngp_fused_kernel(
    const float2* __restrict__ uv,
    const float2* __restrict__ table,
    const float4* __restrict__ w0,
    const float4* __restrict__ w1,
    const float*  __restrict__ w2,
    float* __restrict__ out,
    NGPParams p, int n)
{
    __shared__ float4 sw0[512];
    __shared__ float4 sw1[1024];
    __shared__ float  sw2[192];
    const int t = threadIdx.x;
    #pragma unroll
    for (int i = 0; i < 2; i++) sw0[t + 256 * i] = w0[t + 256 * i];
    #pragma unroll
    for (int i = 0; i < 4; i++) sw1[t + 256 * i] = w1[t + 256 * i];
    if (t < 192) sw2[t] = w2[t];
    __syncthreads();
    const int gi = blockIdx.x * 256 + t;
    if (gi >= n) return;
    const float2 xy = uv[gi];
    float feat[32];
    #pragma unroll
    for (int l = 0; l < NLV; l++) {
        const float s = p.scale[l];
        const unsigned res = p.res[l];
        const float px = xy.x * s + 0.5f;
        const float py = xy.y * s + 0.5f;
        const float fpx = floorf(px), fpy = floorf(py);
        const float fx = px - fpx, fy = py - fpy;
        const unsigned x0 = (unsigned)fpx, y0 = (unsigned)fpy;
        unsigned i00, i10, i01, i11;
        if (!((p.hashed_mask >> l) & 1u)) {
            const unsigned b = x0 + y0 * res;
            i00 = b & TMASK; i10 = (b + 1u) & TMASK;
            i01 = (b + res) & TMASK; i11 = (b + res + 1u) & TMASK;
        } else {
            const unsigned hy0 = y0 * PRIME_Y;
            const unsigned hy1 = (y0 + 1u) * PRIME_Y;
            i00 = (x0 ^ hy0) & TMASK; i10 = ((x0 + 1u) ^ hy0) & TMASK;
            i01 = (x0 ^ hy1) & TMASK; i11 = ((x0 + 1u) ^ hy1) & TMASK;
        }
        const float2* tl = table + ((size_t)l << LOG2T);
        const float2 c00 = tl[i00], c10 = tl[i10], c01 = tl[i01], c11 = tl[i11];
        const float w00 = (1.f - fx) * (1.f - fy);
        const float w10 = fx * (1.f - fy);
        const float w01 = (1.f - fx) * fy;
        const float w11 = fx * fy;
        feat[2 * l]     = w00 * c00.x + w10 * c10.x + w01 * c01.x + w11 * c11.x;
        feat[2 * l + 1] = w00 * c00.y + w10 * c10.y + w01 * c01.y + w11 * c11.y;
    }
    float2 h0[32];
    #pragma unroll
    for (int j = 0; j < 32; j++) h0[j] = make_float2(0.f, 0.f);
    #pragma unroll
    for (int k = 0; k < 32; k++) {
        const float f = feat[k];
        #pragma unroll
        for (int j = 0; j < 16; j++) {
            const float4 ww = sw0[k * 16 + j];
            h0[2 * j].x = fmaf(f, ww.x, h0[2 * j].x);
            h0[2 * j].y = fmaf(f, ww.y, h0[2 * j].y);
            h0[2 * j + 1].x = fmaf(f, ww.z, h0[2 * j + 1].x);
            h0[2 * j + 1].y = fmaf(f, ww.w, h0[2 * j + 1].y);
        }
    }
    #pragma unroll
    for (int j = 0; j < 32; j++) {
        h0[j].x = fmaxf(h0[j].x, 0.f);
        h0[j].y = fmaxf(h0[j].y, 0.f);
    }
    float2 h1[32];
    #pragma unroll
    for (int j = 0; j < 32; j++) h1[j] = make_float2(0.f, 0.f);
    #pragma unroll
    for (int k = 0; k < 64; k++) {
        const float f = (k & 1) ? h0[k >> 1].y : h0[k >> 1].x;
        #pragma unroll
        for (int j = 0; j < 16; j++) {
            const float4 ww = sw1[k * 16 + j];
            h1[2 * j].x = fmaf(f, ww.x, h1[2 * j].x);
            h1[2 * j].y = fmaf(f, ww.y, h1[2 * j].y);
            h1[2 * j + 1].x = fmaf(f, ww.z, h1[2 * j + 1].x);
            h1[2 * j + 1].y = fmaf(f, ww.w, h1[2 * j + 1].y);
        }
    }
    #pragma unroll
    for (int j = 0; j < 32; j++) {
        h1[j].x = fmaxf(h1[j].x, 0.f);
        h1[j].y = fmaxf(h1[j].y, 0.f);
    }
    float z0 = 0.f, z1 = 0.f, z2 = 0.f;
    #pragma unroll
    for (int k = 0; k < 64; k++) {
        const float f = (k & 1) ? h1[k >> 1].y : h1[k >> 1].x;
        z0 = fmaf(f, sw2[3 * k + 0], z0);
        z1 = fmaf(f, sw2[3 * k + 1], z1);
        z2 = fmaf(f, sw2[3 * k + 2], z2);
    }
    out[3 * gi + 0] = 1.f / (1.f + __expf(-z0));
    out[3 * gi + 1] = 1.f / (1.f + __expf(-z1));
    out[3 * gi + 2] = 1.f / (1.f + __expf(-z2));
}

extern "C" void kernel_launch(void* const* d_in, const int* in_sizes, int n_in,
                              void* d_out, int out_size, void* d_ws, size_t ws_size,
                              hipStream_t stream) {
    const float2* uv    = (const float2*)d_in[0];
    const float2* table = (const float2*)d_in[1];
    const float*  w0f   = (const float*)d_in[2];
    const float*  w1f   = (const float*)d_in[3];
    const float*  w2f   = (const float*)d_in[4];
    float* out = (float*)d_out;

    const int n = in_sizes[0] / 2;

    NGPParams p;
    p.hashed_mask = 0;
    const double B = exp((log(2048.0) - log(16.0)) / 15.0);
    for (int l = 0; l < NLV; l++) {
        const double scale = 16.0 * pow(B, (double)l) - 1.0;
        const long long res = (long long)ceil(scale) + 1;
        p.scale[l] = (float)scale;
        p.res[l] = (unsigned)res;
        if (res * res > (long long)TSZ) p.hashed_mask |= (1u << l);
    }

    const size_t xt_bytes   = (size_t)NLV * (size_t)n * 2u;    // fp8 pairs
    const size_t wpf_bytes  = ((size_t)WPF_BYTES + 63u) & ~63ull;
    const size_t suv_bytes  = (size_t)n * 8u;
    const size_t perm_bytes = (size_t)n * 4u;
    const size_t ctl_bytes  = (size_t)NCOARSE * 4u * 2u;   // hist | cursor

    const size_t need_sorted = xt_bytes + wpf_bytes + suv_bytes + perm_bytes + ctl_bytes;
    const size_t need_plain  = xt_bytes + wpf_bytes;

    const int chunks  = (n + 255) / 256;
    const int chunks2 = (n + 511) / 512;

    if (ws_size < need_plain) {          // ultimate fallback
        ngp_fused_kernel<<<chunks, 256, 0, stream>>>(
            uv, table, (const float4*)w0f, (const float4*)w1f, w2f, out, p, n);
        return;
    }

    ushort* xt = (ushort*)d_ws;
    unsigned long long* wp8 = (unsigned long long*)((char*)d_ws + xt_bytes);
    ushort* wp16 = (ushort*)((char*)d_ws + xt_bytes + WP8_BYTES);

    float2*   suv    = (float2*)((char*)d_ws + xt_bytes + wpf_bytes);
    uint32_t* perm   = (uint32_t*)((char*)suv + suv_bytes);
    uint32_t* hist   = (uint32_t*)((char*)perm + perm_bytes);
    uint32_t* cursor = hist + NCOARSE;

    const int mlp_blocks = chunks < 1024 ? chunks : 1024;

    if (ws_size < need_sorted) {         // no-sort path
        ngp_prep_wfrag<<<1, 256, 0, stream>>>(w0f, w1f, w2f, wp8, wp16,
                                              (uint32_t*)nullptr);
        ngp_encode2_kernel<<<5 * chunks2, 256, 0, stream>>>(uv, table, xt, p, n, chunks2);
        ngp_mlp_persist<<<mlp_blocks, 256, 0, stream>>>(xt, wp8, wp16,
                                                        (const uint32_t*)nullptr, out, n, chunks);
        return;
    }

    const int p1_blocks = (n + P1_PTS - 1) / P1_PTS;

    ngp_prep_wfrag<<<1, 256, 0, stream>>>(w0f, w1f, w2f, wp8, wp16, hist);
    ngp_hist512<<<p1_blocks, 1024, 0, stream>>>(uv, hist, n);
    ngp_pass1<<<p1_blocks, 1024, 0, stream>>>(uv, hist, cursor, suv, perm, n);
    ngp_pass2<<<NCOARSE, 1024, 0, stream>>>(hist, suv, perm);
    ngp_encode2_kernel<<<5 * chunks2, 256, 0, stream>>>(suv, table, xt, p, n, chunks2);
    ngp_mlp_persist<<<mlp_blocks, 256, 0, stream>>>(xt, wp8, wp16, perm, out, n, chunks);
}